// Round 1
// baseline (497.377 us; speedup 1.0000x reference)
//
#include <hip/hip_runtime.h>

#define HIDDEN 64

__global__ __launch_bounds__(256) void gine_copy_kernel(const float4* __restrict__ x,
                                                        float4* __restrict__ out, int n4) {
    int i = blockIdx.x * blockDim.x + threadIdx.x;
    int stride = gridDim.x * blockDim.x;
    for (; i < n4; i += stride) out[i] = x[i];
}

// One wave (64 lanes) per edge; lane = hidden channel.
__global__ __launch_bounds__(256) void gine_edge_kernel(const float* __restrict__ x,
                                                        const int* __restrict__ ei,
                                                        const float4* __restrict__ ea,
                                                        const float* __restrict__ We,
                                                        const float* __restrict__ be,
                                                        float* __restrict__ out, int E) {
    const int lane = threadIdx.x & 63;
    // Hoist this lane's edge-projection column into registers (read once).
    const float w0 = We[lane];
    const float w1 = We[64 + lane];
    const float w2 = We[128 + lane];
    const float w3 = We[192 + lane];
    const float bb = be[lane];
    int wave = (blockIdx.x * blockDim.x + threadIdx.x) >> 6;
    const int nw = (gridDim.x * blockDim.x) >> 6;
    for (int e = wave; e < E; e += nw) {
        const int src = ei[e];
        const int dst = ei[E + e];
        const float4 a = ea[e];
        float m = x[src * HIDDEN + lane] + (bb + a.x * w0 + a.y * w1 + a.z * w2 + a.w * w3);
        m = fmaxf(m, 0.0f);
        atomicAdd(out + dst * HIDDEN + lane, m);
    }
}

// One wave per node; W1/W2/b1/b2 staged in LDS; h broadcast via shfl.
// Row-local => safe to run in-place on `out` (out holds h = x + agg on entry).
__global__ __launch_bounds__(256) void gine_mlp_kernel(const float* __restrict__ W1,
                                                       const float* __restrict__ b1,
                                                       const float* __restrict__ W2,
                                                       const float* __restrict__ b2,
                                                       float* __restrict__ out, int N) {
    __shared__ float sW1[64 * 64];
    __shared__ float sW2[64 * 64];
    __shared__ float sb1[64], sb2[64];
    for (int i = threadIdx.x; i < 64 * 64; i += blockDim.x) {
        sW1[i] = W1[i];
        sW2[i] = W2[i];
    }
    if (threadIdx.x < 64) {
        sb1[threadIdx.x] = b1[threadIdx.x];
        sb2[threadIdx.x] = b2[threadIdx.x];
    }
    __syncthreads();
    const int lane = threadIdx.x & 63;
    int wave = (blockIdx.x * blockDim.x + threadIdx.x) >> 6;
    const int nw = (gridDim.x * blockDim.x) >> 6;
    for (int n = wave; n < N; n += nw) {
        const float h = out[n * HIDDEN + lane];
        float t = sb1[lane];
#pragma unroll
        for (int k = 0; k < 64; ++k) t = fmaf(__shfl(h, k), sW1[k * 64 + lane], t);
        t = fmaxf(t, 0.0f);
        float o = sb2[lane];
#pragma unroll
        for (int k = 0; k < 64; ++k) o = fmaf(__shfl(t, k), sW2[k * 64 + lane], o);
        out[n * HIDDEN + lane] = o;
    }
}

extern "C" void kernel_launch(void* const* d_in, const int* in_sizes, int n_in,
                              void* d_out, int out_size, void* d_ws, size_t ws_size,
                              hipStream_t stream) {
    const float* x  = (const float*)d_in[0];
    const int*   ei = (const int*)d_in[1];
    const float* ea = (const float*)d_in[2];
    const float* We = (const float*)d_in[3];
    const float* be = (const float*)d_in[4];
    const float* W1 = (const float*)d_in[5];
    const float* b1 = (const float*)d_in[6];
    const float* W2 = (const float*)d_in[7];
    const float* b2 = (const float*)d_in[8];
    float* out = (float*)d_out;

    const int N = in_sizes[0] / HIDDEN;   // 100000
    const int E = in_sizes[1] / 2;        // 1600000

    // 1) out = x  (agg accumulates on top => h = x + agg)
    gine_copy_kernel<<<2048, 256, 0, stream>>>((const float4*)x, (float4*)out, N * (HIDDEN / 4));
    // 2) scatter-add relu(x[src] + edge_attr@We + be) into out[dst]
    gine_edge_kernel<<<2048, 256, 0, stream>>>(x, ei, (const float4*)ea, We, be, out, E);
    // 3) in-place row-local MLP
    gine_mlp_kernel<<<2048, 256, 0, stream>>>(W1, b1, W2, b2, out, N);
}